// Round 1
// baseline (349.359 us; speedup 1.0000x reference)
//
#include <hip/hip_runtime.h>

#define BB 32
#define NN 384
#define RR 16
#define N4 (NN / 4)                 // 96 float4 per row
#define TOTAL4 (BB * NN * N4)       // 1,179,648
#define BLK 256
#define GRID_MAIN (TOTAL4 / BLK)    // 4608 blocks: exactly 1 float4 per thread

#define LOG2E 1.4426950408889634f
#define LN2   0.6931471805599453f

// softplus(x) = max(x,0) + log1p(exp(-|x|)) via hardware exp2/log2:
//   log1p(exp(-a)) = ln2 * log2(1 + 2^(-a*log2e))
__device__ __forceinline__ float softplus_fast(float x) {
    float a = fabsf(x);
    float e = __builtin_amdgcn_exp2f(-a * LOG2E);        // v_exp_f32
    return fmaxf(x, 0.0f) + LN2 * __builtin_amdgcn_logf(1.0f + e);  // v_log_f32
}

// Reduce {float,int,float,int} across the block; result in lane 0 of wave 0.
__device__ __forceinline__ void blockReduce4(float& f0, int& c0, float& f1, int& c1) {
    #pragma unroll
    for (int off = 32; off > 0; off >>= 1) {
        f0 += __shfl_down(f0, off, 64);
        c0 += __shfl_down(c0, off, 64);
        f1 += __shfl_down(f1, off, 64);
        c1 += __shfl_down(c1, off, 64);
    }
    __shared__ float sf0[16], sf1[16];
    __shared__ int   sc0[16], sc1[16];
    int lane = threadIdx.x & 63;
    int wave = threadIdx.x >> 6;
    if (lane == 0) { sf0[wave] = f0; sc0[wave] = c0; sf1[wave] = f1; sc1[wave] = c1; }
    __syncthreads();
    int nw = blockDim.x >> 6;
    if (wave == 0) {
        f0 = (lane < nw) ? sf0[lane] : 0.0f;
        c0 = (lane < nw) ? sc0[lane] : 0;
        f1 = (lane < nw) ? sf1[lane] : 0.0f;
        c1 = (lane < nw) ? sc1[lane] : 0;
        #pragma unroll
        for (int off = 32; off > 0; off >>= 1) {
            f0 += __shfl_down(f0, off, 64);
            c0 += __shfl_down(c0, off, 64);
            f1 += __shfl_down(f1, off, 64);
            c1 += __shfl_down(c1, off, 64);
        }
    }
}

// Fused: order BCE (every thread owns exactly one float4 of order_logits)
// + relation CE (first B*N threads). Per-block partials -> ws[blockIdx.x].
__global__ __launch_bounds__(BLK) void main_loss_kernel(
        const float* __restrict__ order_logits,
        const float* __restrict__ relation_logits,
        const int* __restrict__ reading_orders,
        const int* __restrict__ parent_ids,
        const int* __restrict__ relations,
        const unsigned char* __restrict__ region_mask,
        float4* __restrict__ ws) {
    const int gid = blockIdx.x * BLK + threadIdx.x;   // == float4 index, < TOTAL4

    // ---- order BCE: this thread's 4 consecutive j's in row (b,i) ----
    float oSum = 0.0f; int oCnt = 0;
    {
        int j4 = (gid % N4) * 4;
        int bi = gid / N4;                    // b*NN + i
        if (region_mask[bi]) {                // invalid row: skip the 16B load too
            int i  = bi % NN;
            int bBase = bi - i;               // b*NN
            int ro_i = reading_orders[bi];
            float4 x4 = ((const float4*)order_logits)[gid];
            uchar4 m4 = *(const uchar4*)(region_mask + bBase + j4);      // 4B aligned
            int4  ro4 = *(const int4*)(reading_orders + bBase + j4);     // 16B aligned
            #pragma unroll
            for (int k = 0; k < 4; ++k) {
                int j = j4 + k;
                float x  = (&x4.x)[k];
                int   mj = (&m4.x)[k];
                int  roj = (&ro4.x)[k];
                if (mj && (i != j)) {
                    float t = (ro_i < roj) ? 1.0f : 0.0f;
                    oSum += softplus_fast(x) - x * t;
                    oCnt++;
                }
            }
        }
    }

    // ---- relation CE: one item per thread for the first B*N threads ----
    float rSum = 0.0f; int rCnt = 0;
    if (gid < BB * NN) {
        int b = gid / NN, i = gid % NN;
        int p = parent_ids[gid];
        int r = relations[gid];
        if (region_mask[gid] && p >= 0 && p < NN && r >= 0) {
            const float4* row =
                (const float4*)(relation_logits + ((size_t)(b * NN + p) * NN + i) * RR);
            float4 a0 = row[0], a1 = row[1], a2 = row[2], a3 = row[3];
            float v[RR];
            v[0]=a0.x;  v[1]=a0.y;  v[2]=a0.z;  v[3]=a0.w;
            v[4]=a1.x;  v[5]=a1.y;  v[6]=a1.z;  v[7]=a1.w;
            v[8]=a2.x;  v[9]=a2.y;  v[10]=a2.z; v[11]=a2.w;
            v[12]=a3.x; v[13]=a3.y; v[14]=a3.z; v[15]=a3.w;
            float m = v[0];
            #pragma unroll
            for (int k = 1; k < RR; ++k) m = fmaxf(m, v[k]);
            // logsumexp via hardware exp2/log2; v[r] picked with STATIC indices
            // (runtime-indexed v[r] forces the array to scratch — rule #20).
            float s = 0.0f, tgt = 0.0f;
            #pragma unroll
            for (int k = 0; k < RR; ++k) {
                s += __builtin_amdgcn_exp2f((v[k] - m) * LOG2E);
                tgt = (k == r) ? v[k] : tgt;     // k literal -> v_cndmask chain
            }
            rSum = m + LN2 * __builtin_amdgcn_logf(s) - tgt;
            rCnt = 1;
        }
    }

    blockReduce4(oSum, oCnt, rSum, rCnt);
    if (threadIdx.x == 0) {
        float4 out;
        out.x = oSum;
        out.y = __int_as_float(oCnt);
        out.z = rSum;
        out.w = __int_as_float(rCnt);
        ws[blockIdx.x] = out;   // overwrites poison; no memset needed
    }
}

// ---- Finalize: reduce GRID_MAIN per-block partials, emit 3 scalars ----
__global__ __launch_bounds__(BLK) void finalize_kernel(const float4* __restrict__ ws,
                                                       float* __restrict__ out) {
    float oSum = 0.0f, rSum = 0.0f;
    int oCnt = 0, rCnt = 0;
    for (int i = threadIdx.x; i < GRID_MAIN; i += BLK) {
        float4 v = ws[i];
        oSum += v.x;
        oCnt += __float_as_int(v.y);
        rSum += v.z;
        rCnt += __float_as_int(v.w);
    }
    blockReduce4(oSum, oCnt, rSum, rCnt);
    if (threadIdx.x == 0) {
        float order_loss = oSum / (float)(oCnt > 1 ? oCnt : 1);
        float rel_loss   = rSum / (float)(rCnt > 1 ? rCnt : 1);
        out[0] = 1.0f * order_loss + 0.5f * rel_loss;  // ORDER_W=1.0, REL_W=0.5
        out[1] = order_loss;
        out[2] = rel_loss;
    }
}

extern "C" void kernel_launch(void* const* d_in, const int* in_sizes, int n_in,
                              void* d_out, int out_size, void* d_ws, size_t ws_size,
                              hipStream_t stream) {
    const float* order_logits    = (const float*)d_in[0];
    const float* relation_logits = (const float*)d_in[1];
    const int* reading_orders    = (const int*)d_in[2];
    const int* parent_ids        = (const int*)d_in[3];
    const int* relations         = (const int*)d_in[4];
    const unsigned char* region_mask = (const unsigned char*)d_in[5];
    float* out  = (float*)d_out;
    float4* ws4 = (float4*)d_ws;

    main_loss_kernel<<<GRID_MAIN, BLK, 0, stream>>>(
        order_logits, relation_logits, reading_orders, parent_ids, relations,
        region_mask, ws4);
    finalize_kernel<<<1, BLK, 0, stream>>>(ws4, out);
}